// Round 8
// baseline (194.869 us; speedup 1.0000x reference)
//
#include <hip/hip_runtime.h>
#include <math.h>

// DeepMMD, round 10: joint symmetric 8192x8192 pass, 128x128 tiles (2080 blocks).
//  - LDS panels now SLOT-MAJOR [slot][128 rows]: ds_read addr16 = g*128+s ->
//    bank quad = s mod 8 -> conflict-free column reads, no XOR swizzle anywhere
//    (gload_lds linear dest maps as thread u -> row u&127, slot u>>7).
//  - org K=64 per iteration (2 subs per stage): 10 -> 6 iterations, 8 MFMA per
//    org iter; dbuf half = 32KB (A 16K + B 16K).
//  - row-sum bank rotation fixed: cc = (c + (q<<1|row&1)) & 7.
//  - math identical to r9: org dot pure-f16 (exact fp64 norms in wOrg), feat
//    dot hi/lo 3-product, MFMA accumulation order unchanged -> bit-identical.

#define N_S 4096
#define LOG2E 1.4426950408889634

typedef _Float16 v8h __attribute__((ext_vector_type(8)));
typedef float v16f __attribute__((ext_vector_type(16)));

union U16 { uint4 u; v8h h; };

__device__ __forceinline__ void pack_hilo(const float* fv, uint4* hi, uint4* lo) {
    U16 H, L;
#pragma unroll
    for (int u = 0; u < 8; ++u) {
        _Float16 h = (_Float16)fv[u];
        H.h[u] = h;
        L.h[u] = (_Float16)(fv[u] - (float)h);
    }
    *hi = H.u; *lo = L.u;
}

__device__ __forceinline__ uint4 pack_hi(const float* fv) {
    U16 H;
#pragma unroll
    for (int u = 0; u < 8; ++u) H.h[u] = (_Float16)fv[u];
    return H.u;
}

__device__ __forceinline__ void gload16(const void* g, void* lds) {
    __builtin_amdgcn_global_load_lds(
        (const __attribute__((address_space(1))) unsigned int*)g,
        (__attribute__((address_space(3))) unsigned int*)lds, 16, 0, 0);
}

// ---------------- MLP (fp64 internals), 8-way k-split ----------------
// -> PK[8192][48] uint4: org subs t=0..7 at t*4+slot (hi only, linear),
//    feat subs t=8,9 at 32+(t-8)*8: slots 0-3 hi, 4-7 lo.
// also normF[8192], wOrg[8192]; zeroes D8[8192] and S[4].
__global__ __launch_bounds__(256)
void mlp_kernel(const float* __restrict__ X, const float* __restrict__ Y,
                const float* __restrict__ W1, const float* __restrict__ b1,
                const float* __restrict__ W2, const float* __restrict__ b2,
                const float* __restrict__ W3, const float* __restrict__ b3,
                const float* __restrict__ W4, const float* __restrict__ b4,
                const float* __restrict__ sq,
                uint4* __restrict__ PK, float* __restrict__ normF,
                float* __restrict__ wOrg,
                float* __restrict__ D8, double* __restrict__ S)
{
    __shared__ double sW1[8 * 330];
    __shared__ double sW2[100], sW3[100], sW4[500];
    __shared__ double sb1[10], sb2[10], sb3[10], sb4[50];
    int tid = threadIdx.x;
    int gt = blockIdx.x * 256 + tid;

    // workspace zeroing (replaces hipMemsetAsync)
    if (gt < 8192) D8[gt] = 0.0f;
    else if (gt < 8196) S[gt - 8192] = 0.0;

    {
        int kg = tid >> 5, kl = tid & 31;
#pragma unroll
        for (int j = 0; j < 10; ++j)
            sW1[kg * 330 + kl * 10 + j] = (double)W1[tid * 10 + j];
    }
    for (int i = tid; i < 100; i += 256) { sW2[i] = (double)W2[i]; sW3[i] = (double)W3[i]; }
    for (int i = tid; i < 500; i += 256) sW4[i] = (double)W4[i];
    if (tid < 10) { sb1[tid] = (double)b1[tid]; sb2[tid] = (double)b2[tid]; sb3[tid] = (double)b3[tid]; }
    if (tid < 50) sb4[tid] = (double)b4[tid];
    __syncthreads();

    int r = gt >> 3, g = gt & 7;
    const float* xr = (r < N_S) ? (X + (size_t)r * 256) : (Y + (size_t)(r - N_S) * 256);
    const float* xrg = xr + g * 32;
    const double* w1g = sW1 + g * 330;

    float xl[32];
    double z[10];
#pragma unroll
    for (int j = 0; j < 10; ++j) z[j] = 0.0;
    double nrm = 0.0;
    for (int k4 = 0; k4 < 32; k4 += 4) {
        float4 xv4 = *(const float4*)(xrg + k4);
        xl[k4] = xv4.x; xl[k4 + 1] = xv4.y; xl[k4 + 2] = xv4.z; xl[k4 + 3] = xv4.w;
        double xv[4] = {(double)xv4.x, (double)xv4.y, (double)xv4.z, (double)xv4.w};
#pragma unroll
        for (int u = 0; u < 4; ++u) {
            nrm += xv[u] * xv[u];
#pragma unroll
            for (int j = 0; j < 10; ++j) z[j] += xv[u] * w1g[(k4 + u) * 10 + j];
        }
    }
    // pack org sub-block g: 4 k-groups, hi only, linear slots
    {
        size_t base = (size_t)r * 48 + g * 4;
#pragma unroll
        for (int u = 0; u < 4; ++u)
            PK[base + u] = pack_hi(&xl[u * 8]);
    }

#pragma unroll
    for (int off = 1; off < 8; off <<= 1) {
        nrm += __shfl_xor(nrm, off);
#pragma unroll
        for (int j = 0; j < 10; ++j) z[j] += __shfl_xor(z[j], off);
    }
#pragma unroll
    for (int j = 0; j < 10; ++j) z[j] += sb1[j];
#pragma unroll
    for (int j = 0; j < 10; ++j) z[j] = fmax(z[j], 0.0) + log1p(exp(-fabs(z[j])));

    double z2[10];
#pragma unroll
    for (int j = 0; j < 10; ++j) z2[j] = sb2[j];
#pragma unroll
    for (int k = 0; k < 10; ++k)
#pragma unroll
        for (int j = 0; j < 10; ++j) z2[j] += z[k] * sW2[k * 10 + j];
#pragma unroll
    for (int j = 0; j < 10; ++j) z2[j] = fmax(z2[j], 0.0) + log1p(exp(-fabs(z2[j])));

    double z3[10];
#pragma unroll
    for (int j = 0; j < 10; ++j) z3[j] = sb3[j];
#pragma unroll
    for (int k = 0; k < 10; ++k)
#pragma unroll
        for (int j = 0; j < 10; ++j) z3[j] += z2[k] * sW3[k * 10 + j];
#pragma unroll
    for (int j = 0; j < 10; ++j) z3[j] = fmax(z3[j], 0.0) + log1p(exp(-fabs(z3[j])));

    // all 8 lanes compute all 50 f values (identical fp64); lane g keeps j in [8g,8g+8)
    double nf = 0.0;
    float ff[8];
#pragma unroll
    for (int u = 0; u < 8; ++u) ff[u] = 0.0f;
#pragma unroll
    for (int j = 0; j < 50; ++j) {
        double f = sb4[j];
#pragma unroll
        for (int k = 0; k < 10; ++k) f += z3[k] * sW4[k * 50 + j];
        nf += f * f;
        if ((j >> 3) == g) ff[j & 7] = (float)f;
    }
    {
        uint4 hi, lo;
        pack_hilo(ff, &hi, &lo);
        size_t fb = (size_t)r * 48 + 32 + (g >> 2) * 8 + (g & 3);
        PK[fb] = hi;
        PK[fb + 4] = lo;
    }

    if (g == 0) {
        double sqv = (double)sq[0];
        double co = LOG2E / (sqv * sqv);
        wOrg[r] = (float)exp2(-nrm * co);
    }
    if (g == 1) normF[r] = (float)nf;
}

// ---------------- helpers ----------------
// slot-major LDS read: buf[g*128 + s] (conflict-free: bank quad = s mod 8)
__device__ __forceinline__ v8h ldsm(const uint4* buf, int s, int g) {
    U16 t; t.u = buf[g * 128 + s];
    return t.h;
}

// ---------------- joint pairwise pass (512 threads / 8 waves) ----------------
__global__ __launch_bounds__(512, 4)
void pair_kernel(const uint4* __restrict__ PK, const float* __restrict__ normF,
                 const float* __restrict__ wOrg,
                 const float* __restrict__ ep, const float* __restrict__ sq,
                 const float* __restrict__ sph,
                 float* __restrict__ D8, double* __restrict__ S)
{
    // LDS: dbuf half hb at smem+hb*32768:
    //   org iter (K=64): A[8][128]u4 (16K) @0 + B (16K) @16384
    //   feat iter:       A[8][128]u4 (hi 0-3, lo 4-7) + B, same geometry
    // epilogue: E2[128][128] f32 = 65536; dred 16 f64 (overlaid)
    __shared__ __align__(16) char smem[65536];

    int tid = threadIdx.x;
    int lane = tid & 63, w = tid >> 6;
    int wr2 = w >> 2, wc4 = w & 3;          // wave grid: 2 row-halves x 4 col-quarters

    // XCD-chunked swizzle (2080 = 8 * 260, bijective) + closed-form triangle decode
    int orig = blockIdx.x;
    int L = (orig & 7) * 260 + (orig >> 3);
    int it = (int)((129.0 - sqrt(16641.0 - 8.0 * (double)L)) * 0.5);
    while (it * (129 - it) / 2 > L) --it;
    while ((it + 1) * (128 - it) / 2 <= L) ++it;
    int jt = it + (L - it * (129 - it) / 2);
    int i0 = it * 128, j0 = jt * 128;

    // stage iteration t into buffer half hb: linear LDS dest addr16 = u,
    // thread u stages row u&127, slot u>>7 (slot-major, no swizzle).
    //   t<4: org K=64 (subs 2t,2t+1): src slot q*8+s8
    //   t>=4: feat sub t-4: src 32+(t-4)*8+s8
    auto stage = [&](int t, int hb) {
        char* Ab = smem + hb * 32768;
        char* Bb = Ab + 16384;
        int soff = (t < 4) ? t * 8 : 32 + (t - 4) * 8;
#pragma unroll
        for (int i = 0; i < 2; ++i) {
            int u = i * 512 + tid;
            int row = u & 127, s8 = u >> 7;
            const uint4* ga = &PK[(size_t)(i0 + row) * 48 + soff + s8];
            const uint4* gb = &PK[(size_t)(j0 + row) * 48 + soff + s8];
            char* la = Ab + (i * 512 + (w << 6)) * 16;   // wave-uniform base
            char* lb = Bb + (i * 512 + (w << 6)) * 16;
            gload16(ga, la);
            gload16(gb, lb);
        }
    };

    stage(0, 0);        // first loads fly while scalar setup below executes

    bool sameHalf = (jt < 32) || (it >= 32);
    bool isDiag = (it == jt);
    bool isTrace = (jt == it + 32);
    int region = (jt < 32) ? 0 : ((it >= 32) ? 1 : 2);
    float sgn = sameHalf ? 1.0f : -1.0f;

    int rs0 = wr2 * 64 + (lane & 31), rs1 = rs0 + 32;
    int cs = wc4 * 32 + (lane & 31);

    // org: pure f16 single product, K=64 -> 4 ks x 2 MFMA
    auto mfma_org = [&](int hb, v16f& a0, v16f& a1) {
        const uint4* Ab = (const uint4*)(smem + hb * 32768);
        const uint4* Bb = (const uint4*)(smem + hb * 32768 + 16384);
#pragma unroll
        for (int ks = 0; ks < 4; ++ks) {
            int gl = ks * 2 + (lane >> 5);
            v8h ah0 = ldsm(Ab, rs0, gl), ah1 = ldsm(Ab, rs1, gl);
            v8h bh = ldsm(Bb, cs, gl);
            a0 = __builtin_amdgcn_mfma_f32_32x32x16_f16(ah0, bh, a0, 0, 0, 0);
            a1 = __builtin_amdgcn_mfma_f32_32x32x16_f16(ah1, bh, a1, 0, 0, 0);
        }
    };
    // feat: hi/lo 3-product (hi slots 0-3, lo slots 4-7)
    auto mfma_feat = [&](int hb, v16f& a0, v16f& a1) {
        const uint4* Ab = (const uint4*)(smem + hb * 32768);
        const uint4* Bb = (const uint4*)(smem + hb * 32768 + 16384);
#pragma unroll
        for (int ks = 0; ks < 2; ++ks) {
            int gl = ks * 2 + (lane >> 5);
            v8h ah0 = ldsm(Ab, rs0, gl), ah1 = ldsm(Ab, rs1, gl);
            v8h al0 = ldsm(Ab, rs0, 4 + gl), al1 = ldsm(Ab, rs1, 4 + gl);
            v8h bh = ldsm(Bb, cs, gl), bl = ldsm(Bb, cs, 4 + gl);
            a0 = __builtin_amdgcn_mfma_f32_32x32x16_f16(al0, bh, a0, 0, 0, 0);
            a0 = __builtin_amdgcn_mfma_f32_32x32x16_f16(ah0, bl, a0, 0, 0, 0);
            a0 = __builtin_amdgcn_mfma_f32_32x32x16_f16(ah0, bh, a0, 0, 0, 0);
            a1 = __builtin_amdgcn_mfma_f32_32x32x16_f16(al1, bh, a1, 0, 0, 0);
            a1 = __builtin_amdgcn_mfma_f32_32x32x16_f16(ah1, bl, a1, 0, 0, 0);
            a1 = __builtin_amdgcn_mfma_f32_32x32x16_f16(ah1, bh, a1, 0, 0, 0);
        }
    };

    v16f accG0{}, accG1{}, accF0{}, accF1{};

    // ---- K-loop: 4 org (K=64) + 2 feat iterations, ONE barrier/iter ----
    // body t: [vmcnt(0) own t-loads; barrier (=> all waves' t-loads landed AND
    // all waves done MFMA(t-1) on hb^1); stage(t+1) into hb^1; MFMA(t) on hb]
#pragma unroll
    for (int t = 0; t < 6; ++t) {
        int hb = t & 1;
        asm volatile("s_waitcnt vmcnt(0)" ::: "memory");
        __builtin_amdgcn_sched_barrier(0);
        __builtin_amdgcn_s_barrier();
        __builtin_amdgcn_sched_barrier(0);
        if (t < 5) stage(t + 1, hb ^ 1);
        __builtin_amdgcn_s_setprio(1);
        if (t < 4) mfma_org(hb, accG0, accG1);
        else       mfma_feat(hb, accF0, accF1);
        __builtin_amdgcn_s_setprio(0);
    }
    __syncthreads();    // all waves' ds_reads done before E2 overwrites buffers

    // scalar params
    double epd = (double)ep[0];
    double eps = 1.0 / (1.0 + exp(-epd));
    double sqv = (double)sq[0], spv = (double)sph[0];
    float cf = (float)(LOG2E / (spv * spv));            // feature exponent scale
    float twoco = (float)(2.0 * LOG2E / (sqv * sqv));   // org dot exponent scale
    float epsv = (float)eps, ome = (float)(1.0 - eps);

    // ---- epilogue: kernel values in-register, E2 LDS tile for row sums ----
    float* E2 = (float*)smem;

    double bsum = 0.0, trsum = 0.0;
    float colacc = 0.0f;
    int cl = wc4 * 32 + (lane & 31);
    float wb = wOrg[j0 + cl];
    float nbF = normF[j0 + cl];

    auto evalacc = [&](const v16f& aG, const v16f& aF, int rbase) {
        float4 wa4[4], na4[4];
#pragma unroll
        for (int q = 0; q < 4; ++q) {
            int rb = i0 + rbase + 4 * (lane >> 5) + 8 * q;
            wa4[q] = *(const float4*)&wOrg[rb];
            na4[q] = *(const float4*)&normF[rb];
        }
#pragma unroll
        for (int reg = 0; reg < 16; ++reg) {
            int rl = rbase + 4 * (lane >> 5) + (reg & 3) + 8 * (reg >> 2);
            float wa = ((const float*)&wa4[reg >> 2])[reg & 3];
            float naA = ((const float*)&na4[reg >> 2])[reg & 3];
            float dfeat = fmaxf(naA + nbF - 2.0f * aF[reg], 0.0f);
            float e2v = exp2f(-dfeat * cf);
            float kv = wa * wb * exp2f(aG[reg] * twoco) * (ome * e2v + epsv);
            if (isDiag && rl == cl) kv = 0.0f;
            if (isTrace && cl == rl) trsum += (double)kv;
            bsum += (double)kv;
            colacc += kv;
            E2[rl * 128 + cl] = kv;
        }
    };
    evalacc(accG0, accF0, wr2 * 64);
    evalacc(accG1, accF1, wr2 * 64 + 32);
    __syncthreads();

    // row sums: 4 threads per row; rotation (q<<1|row&1) -> 8 distinct bank
    // quads per 8-lane group (conflict-free)
    {
        int row = tid >> 2, q = tid & 3;
        int rot = ((q << 1) | (row & 1));
        float s = 0.0f;
#pragma unroll
        for (int c = 0; c < 8; ++c) {
            int cc = (c + rot) & 7;
            float4 v = *(const float4*)&E2[row * 128 + q * 32 + cc * 4];
            s += v.x + v.y + v.z + v.w;
        }
        s += __shfl_xor(s, 1);
        s += __shfl_xor(s, 2);
        if (q == 0) atomicAdd(&D8[i0 + row], sgn * s);
    }

    // column sums (skip for diagonal tiles: rows already cover both triangles)
    if (!isDiag) {
        atomicAdd(&D8[j0 + cl], sgn * colacc);
    }

    // block reduce bsum (+ trace): wave shuffle then 8-way LDS
#pragma unroll
    for (int off = 32; off > 0; off >>= 1) bsum += __shfl_down(bsum, off);
    if (isTrace) {
#pragma unroll
        for (int off = 32; off > 0; off >>= 1) trsum += __shfl_down(trsum, off);
    }
    __syncthreads();               // E2 reads done; reuse smem as dred
    double* dred = (double*)smem;
    if (lane == 0) { dred[w] = bsum; dred[8 + w] = trsum; }
    __syncthreads();
    if (tid == 0) {
        double wgt = (sameHalf && !isDiag) ? 2.0 : 1.0;
        double t0 = 0.0, t1 = 0.0;
#pragma unroll
        for (int q = 0; q < 8; ++q) { t0 += dred[q]; t1 += dred[8 + q]; }
        atomicAdd(&S[region], wgt * t0);
        if (isTrace) atomicAdd(&S[3], t1);
    }
}

// ---------------- final scalar assembly ----------------
__global__ __launch_bounds__(256)
void final_kernel(const float* __restrict__ D8, const double* __restrict__ S,
                  float* __restrict__ out)
{
    __shared__ double buf[512];
    int tid = threadIdx.x;
    double sD = 0, sD2 = 0;
    for (int i = tid; i < 4096; i += 256) {
        double d = (double)D8[i] + (double)D8[i + 4096];
        sD += d; sD2 += d * d;
    }
    buf[tid] = sD; buf[256 + tid] = sD2;
    __syncthreads();
    for (int s = 128; s > 0; s >>= 1) {
        if (tid < s) { buf[tid] += buf[tid + s]; buf[256 + tid] += buf[256 + tid + s]; }
        __syncthreads();
    }
    if (tid == 0) {
        double n = (double)N_S, D = n * (n - 1.0);
        double xx = S[0] / D, yy = S[1] / D, xy = (S[2] - S[3]) / D;
        double mmd2 = xx - 2.0 * xy + yy;
        double sumd = buf[0], sumd2 = buf[256];
        double sumh = 2.0 * n + sumd;                    // hs_i = 2 + delta_i
        double sumhs2 = 4.0 * n + 4.0 * sumd + sumd2;
        double n3 = n * n * n, n4 = n3 * n;
        double var = 4.0 / n3 * sumhs2 - 4.0 / n4 * sumh * sumh + 1e-8;
        out[0] = (float)mmd2;
        out[1] = (float)var;
    }
}

extern "C" void kernel_launch(void* const* d_in, const int* in_sizes, int n_in,
                              void* d_out, int out_size, void* d_ws, size_t ws_size,
                              hipStream_t stream)
{
    const float* X   = (const float*)d_in[0];
    const float* Y   = (const float*)d_in[1];
    const float* W1  = (const float*)d_in[2];
    const float* b1  = (const float*)d_in[3];
    const float* W2  = (const float*)d_in[4];
    const float* b2  = (const float*)d_in[5];
    const float* W3  = (const float*)d_in[6];
    const float* b3  = (const float*)d_in[7];
    const float* W4  = (const float*)d_in[8];
    const float* b4  = (const float*)d_in[9];
    const float* ep  = (const float*)d_in[10];
    const float* sq  = (const float*)d_in[11];
    const float* sph = (const float*)d_in[12];
    float* out = (float*)d_out;

    char* ws = (char*)d_ws;
    uint4*  PK    = (uint4*)ws;                       // 8192*48*16 = 6291456
    float*  wOrg  = (float*)(ws + 6291456);           // 32768
    float*  normF = (float*)(ws + 6324224);           // 32768
    float*  D8    = (float*)(ws + 6356992);           // 32768
    double* S     = (double*)(ws + 6389760);          // 32 (Sxx, Syy, Sxy, trace)

    mlp_kernel<<<256, 256, 0, stream>>>(X, Y, W1, b1, W2, b2, W3, b3, W4, b4,
                                        sq, PK, normF, wOrg, D8, S);

    pair_kernel<<<2080, 512, 0, stream>>>(PK, normF, wOrg, ep, sq, sph, D8, S);

    final_kernel<<<1, 256, 0, stream>>>(D8, S, out);
}

// Round 9
// 176.624 us; speedup vs baseline: 1.1033x; 1.1033x over previous
//
#include <hip/hip_runtime.h>
#include <math.h>

// DeepMMD, round 11: joint symmetric 8192x8192 pass, 128x128 tiles (2080 blocks).
//  - PK now TRANSPOSED in global: PKT[48 slot-cols][8192 rows] uint4. Staging
//    (linear LDS dest, thread u -> slot u>>7, row u&127) reads consecutive
//    16B elements per lane -> fully coalesced 2KB segments (fixes r10's 768B-
//    stride scatter, the isolated regression), while LDS stays slot-major
//    [slot][128] -> conflict-free ds_reads (proven: 11.7M -> 532K).
//  - everything else identical to r10: org K=64 iters, one barrier/iter,
//    pure-f16 org dot + exact fp64 norms, feat hi/lo 3-product, XCD swizzle.
//  - math unchanged -> absmax bit-identical.

#define N_S 4096
#define LOG2E 1.4426950408889634

typedef _Float16 v8h __attribute__((ext_vector_type(8)));
typedef float v16f __attribute__((ext_vector_type(16)));

union U16 { uint4 u; v8h h; };

__device__ __forceinline__ void pack_hilo(const float* fv, uint4* hi, uint4* lo) {
    U16 H, L;
#pragma unroll
    for (int u = 0; u < 8; ++u) {
        _Float16 h = (_Float16)fv[u];
        H.h[u] = h;
        L.h[u] = (_Float16)(fv[u] - (float)h);
    }
    *hi = H.u; *lo = L.u;
}

__device__ __forceinline__ uint4 pack_hi(const float* fv) {
    U16 H;
#pragma unroll
    for (int u = 0; u < 8; ++u) H.h[u] = (_Float16)fv[u];
    return H.u;
}

__device__ __forceinline__ void gload16(const void* g, void* lds) {
    __builtin_amdgcn_global_load_lds(
        (const __attribute__((address_space(1))) unsigned int*)g,
        (__attribute__((address_space(3))) unsigned int*)lds, 16, 0, 0);
}

// ---------------- MLP (fp64 internals), 8-way k-split ----------------
// -> PKT[48][8192] uint4 (column-major fragments): org cols 0..31 (slot g*4+u,
//    hi only), feat cols 32..47 (32+(g>>2)*8+(g&3) hi, +4 lo).
// also normF[8192], wOrg[8192]; zeroes D8[8192] and S[4].
__global__ __launch_bounds__(256)
void mlp_kernel(const float* __restrict__ X, const float* __restrict__ Y,
                const float* __restrict__ W1, const float* __restrict__ b1,
                const float* __restrict__ W2, const float* __restrict__ b2,
                const float* __restrict__ W3, const float* __restrict__ b3,
                const float* __restrict__ W4, const float* __restrict__ b4,
                const float* __restrict__ sq,
                uint4* __restrict__ PKT, float* __restrict__ normF,
                float* __restrict__ wOrg,
                float* __restrict__ D8, double* __restrict__ S)
{
    __shared__ double sW1[8 * 330];
    __shared__ double sW2[100], sW3[100], sW4[500];
    __shared__ double sb1[10], sb2[10], sb3[10], sb4[50];
    int tid = threadIdx.x;
    int gt = blockIdx.x * 256 + tid;

    // workspace zeroing (replaces hipMemsetAsync)
    if (gt < 8192) D8[gt] = 0.0f;
    else if (gt < 8196) S[gt - 8192] = 0.0;

    {
        int kg = tid >> 5, kl = tid & 31;
#pragma unroll
        for (int j = 0; j < 10; ++j)
            sW1[kg * 330 + kl * 10 + j] = (double)W1[tid * 10 + j];
    }
    for (int i = tid; i < 100; i += 256) { sW2[i] = (double)W2[i]; sW3[i] = (double)W3[i]; }
    for (int i = tid; i < 500; i += 256) sW4[i] = (double)W4[i];
    if (tid < 10) { sb1[tid] = (double)b1[tid]; sb2[tid] = (double)b2[tid]; sb3[tid] = (double)b3[tid]; }
    if (tid < 50) sb4[tid] = (double)b4[tid];
    __syncthreads();

    int r = gt >> 3, g = gt & 7;
    const float* xr = (r < N_S) ? (X + (size_t)r * 256) : (Y + (size_t)(r - N_S) * 256);
    const float* xrg = xr + g * 32;
    const double* w1g = sW1 + g * 330;

    float xl[32];
    double z[10];
#pragma unroll
    for (int j = 0; j < 10; ++j) z[j] = 0.0;
    double nrm = 0.0;
    for (int k4 = 0; k4 < 32; k4 += 4) {
        float4 xv4 = *(const float4*)(xrg + k4);
        xl[k4] = xv4.x; xl[k4 + 1] = xv4.y; xl[k4 + 2] = xv4.z; xl[k4 + 3] = xv4.w;
        double xv[4] = {(double)xv4.x, (double)xv4.y, (double)xv4.z, (double)xv4.w};
#pragma unroll
        for (int u = 0; u < 4; ++u) {
            nrm += xv[u] * xv[u];
#pragma unroll
            for (int j = 0; j < 10; ++j) z[j] += xv[u] * w1g[(k4 + u) * 10 + j];
        }
    }
    // pack org fragments: columns g*4+u, row r
    {
#pragma unroll
        for (int u = 0; u < 4; ++u)
            PKT[(size_t)(g * 4 + u) * 8192 + r] = pack_hi(&xl[u * 8]);
    }

#pragma unroll
    for (int off = 1; off < 8; off <<= 1) {
        nrm += __shfl_xor(nrm, off);
#pragma unroll
        for (int j = 0; j < 10; ++j) z[j] += __shfl_xor(z[j], off);
    }
#pragma unroll
    for (int j = 0; j < 10; ++j) z[j] += sb1[j];
#pragma unroll
    for (int j = 0; j < 10; ++j) z[j] = fmax(z[j], 0.0) + log1p(exp(-fabs(z[j])));

    double z2[10];
#pragma unroll
    for (int j = 0; j < 10; ++j) z2[j] = sb2[j];
#pragma unroll
    for (int k = 0; k < 10; ++k)
#pragma unroll
        for (int j = 0; j < 10; ++j) z2[j] += z[k] * sW2[k * 10 + j];
#pragma unroll
    for (int j = 0; j < 10; ++j) z2[j] = fmax(z2[j], 0.0) + log1p(exp(-fabs(z2[j])));

    double z3[10];
#pragma unroll
    for (int j = 0; j < 10; ++j) z3[j] = sb3[j];
#pragma unroll
    for (int k = 0; k < 10; ++k)
#pragma unroll
        for (int j = 0; j < 10; ++j) z3[j] += z2[k] * sW3[k * 10 + j];
#pragma unroll
    for (int j = 0; j < 10; ++j) z3[j] = fmax(z3[j], 0.0) + log1p(exp(-fabs(z3[j])));

    // all 8 lanes compute all 50 f values (identical fp64); lane g keeps j in [8g,8g+8)
    double nf = 0.0;
    float ff[8];
#pragma unroll
    for (int u = 0; u < 8; ++u) ff[u] = 0.0f;
#pragma unroll
    for (int j = 0; j < 50; ++j) {
        double f = sb4[j];
#pragma unroll
        for (int k = 0; k < 10; ++k) f += z3[k] * sW4[k * 50 + j];
        nf += f * f;
        if ((j >> 3) == g) ff[j & 7] = (float)f;
    }
    {
        uint4 hi, lo;
        pack_hilo(ff, &hi, &lo);
        int colh = 32 + (g >> 2) * 8 + (g & 3);
        PKT[(size_t)colh * 8192 + r] = hi;
        PKT[(size_t)(colh + 4) * 8192 + r] = lo;
    }

    if (g == 0) {
        double sqv = (double)sq[0];
        double co = LOG2E / (sqv * sqv);
        wOrg[r] = (float)exp2(-nrm * co);
    }
    if (g == 1) normF[r] = (float)nf;
}

// ---------------- helpers ----------------
// slot-major LDS read: buf[g*128 + s] (conflict-free: bank quad = s mod 8)
__device__ __forceinline__ v8h ldsm(const uint4* buf, int s, int g) {
    U16 t; t.u = buf[g * 128 + s];
    return t.h;
}

// ---------------- joint pairwise pass (512 threads / 8 waves) ----------------
__global__ __launch_bounds__(512, 4)
void pair_kernel(const uint4* __restrict__ PKT, const float* __restrict__ normF,
                 const float* __restrict__ wOrg,
                 const float* __restrict__ ep, const float* __restrict__ sq,
                 const float* __restrict__ sph,
                 float* __restrict__ D8, double* __restrict__ S)
{
    // LDS: dbuf half hb at smem+hb*32768:
    //   org iter (K=64): A[8][128]u4 (16K) @0 + B (16K) @16384
    //   feat iter:       A[8][128]u4 (hi 0-3, lo 4-7) + B, same geometry
    // epilogue: E2[128][128] f32 = 65536; dred 16 f64 (overlaid)
    __shared__ __align__(16) char smem[65536];

    int tid = threadIdx.x;
    int lane = tid & 63, w = tid >> 6;
    int wr2 = w >> 2, wc4 = w & 3;          // wave grid: 2 row-halves x 4 col-quarters

    // XCD-chunked swizzle (2080 = 8 * 260, bijective) + closed-form triangle decode
    int orig = blockIdx.x;
    int L = (orig & 7) * 260 + (orig >> 3);
    int it = (int)((129.0 - sqrt(16641.0 - 8.0 * (double)L)) * 0.5);
    while (it * (129 - it) / 2 > L) --it;
    while ((it + 1) * (128 - it) / 2 <= L) ++it;
    int jt = it + (L - it * (129 - it) / 2);
    int i0 = it * 128, j0 = jt * 128;

    // stage iteration t into buffer half hb: linear LDS dest addr16 = u,
    // thread u -> slot u>>7, row u&127; global src PKT[col][i0/j0 + row] ->
    // consecutive lanes read consecutive 16B (fully coalesced 2KB segments).
    auto stage = [&](int t, int hb) {
        char* Ab = smem + hb * 32768;
        char* Bb = Ab + 16384;
        int soff = (t < 4) ? t * 8 : 32 + (t - 4) * 8;
#pragma unroll
        for (int i = 0; i < 2; ++i) {
            int u = i * 512 + tid;
            int row = u & 127, s8 = u >> 7;
            const uint4* ga = &PKT[(size_t)(soff + s8) * 8192 + i0 + row];
            const uint4* gb = &PKT[(size_t)(soff + s8) * 8192 + j0 + row];
            char* la = Ab + (i * 512 + (w << 6)) * 16;   // wave-uniform base
            char* lb = Bb + (i * 512 + (w << 6)) * 16;
            gload16(ga, la);
            gload16(gb, lb);
        }
    };

    stage(0, 0);        // first loads fly while scalar setup below executes

    bool sameHalf = (jt < 32) || (it >= 32);
    bool isDiag = (it == jt);
    bool isTrace = (jt == it + 32);
    int region = (jt < 32) ? 0 : ((it >= 32) ? 1 : 2);
    float sgn = sameHalf ? 1.0f : -1.0f;

    int rs0 = wr2 * 64 + (lane & 31), rs1 = rs0 + 32;
    int cs = wc4 * 32 + (lane & 31);

    // org: pure f16 single product, K=64 -> 4 ks x 2 MFMA
    auto mfma_org = [&](int hb, v16f& a0, v16f& a1) {
        const uint4* Ab = (const uint4*)(smem + hb * 32768);
        const uint4* Bb = (const uint4*)(smem + hb * 32768 + 16384);
#pragma unroll
        for (int ks = 0; ks < 4; ++ks) {
            int gl = ks * 2 + (lane >> 5);
            v8h ah0 = ldsm(Ab, rs0, gl), ah1 = ldsm(Ab, rs1, gl);
            v8h bh = ldsm(Bb, cs, gl);
            a0 = __builtin_amdgcn_mfma_f32_32x32x16_f16(ah0, bh, a0, 0, 0, 0);
            a1 = __builtin_amdgcn_mfma_f32_32x32x16_f16(ah1, bh, a1, 0, 0, 0);
        }
    };
    // feat: hi/lo 3-product (hi slots 0-3, lo slots 4-7)
    auto mfma_feat = [&](int hb, v16f& a0, v16f& a1) {
        const uint4* Ab = (const uint4*)(smem + hb * 32768);
        const uint4* Bb = (const uint4*)(smem + hb * 32768 + 16384);
#pragma unroll
        for (int ks = 0; ks < 2; ++ks) {
            int gl = ks * 2 + (lane >> 5);
            v8h ah0 = ldsm(Ab, rs0, gl), ah1 = ldsm(Ab, rs1, gl);
            v8h al0 = ldsm(Ab, rs0, 4 + gl), al1 = ldsm(Ab, rs1, 4 + gl);
            v8h bh = ldsm(Bb, cs, gl), bl = ldsm(Bb, cs, 4 + gl);
            a0 = __builtin_amdgcn_mfma_f32_32x32x16_f16(al0, bh, a0, 0, 0, 0);
            a0 = __builtin_amdgcn_mfma_f32_32x32x16_f16(ah0, bl, a0, 0, 0, 0);
            a0 = __builtin_amdgcn_mfma_f32_32x32x16_f16(ah0, bh, a0, 0, 0, 0);
            a1 = __builtin_amdgcn_mfma_f32_32x32x16_f16(al1, bh, a1, 0, 0, 0);
            a1 = __builtin_amdgcn_mfma_f32_32x32x16_f16(ah1, bl, a1, 0, 0, 0);
            a1 = __builtin_amdgcn_mfma_f32_32x32x16_f16(ah1, bh, a1, 0, 0, 0);
        }
    };

    v16f accG0{}, accG1{}, accF0{}, accF1{};

    // ---- K-loop: 4 org (K=64) + 2 feat iterations, ONE barrier/iter ----
    // body t: [vmcnt(0) own t-loads; barrier (=> all waves' t-loads landed AND
    // all waves done MFMA(t-1) on hb^1); stage(t+1) into hb^1; MFMA(t) on hb]
#pragma unroll
    for (int t = 0; t < 6; ++t) {
        int hb = t & 1;
        asm volatile("s_waitcnt vmcnt(0)" ::: "memory");
        __builtin_amdgcn_sched_barrier(0);
        __builtin_amdgcn_s_barrier();
        __builtin_amdgcn_sched_barrier(0);
        if (t < 5) stage(t + 1, hb ^ 1);
        __builtin_amdgcn_s_setprio(1);
        if (t < 4) mfma_org(hb, accG0, accG1);
        else       mfma_feat(hb, accF0, accF1);
        __builtin_amdgcn_s_setprio(0);
    }
    __syncthreads();    // all waves' ds_reads done before E2 overwrites buffers

    // scalar params
    double epd = (double)ep[0];
    double eps = 1.0 / (1.0 + exp(-epd));
    double sqv = (double)sq[0], spv = (double)sph[0];
    float cf = (float)(LOG2E / (spv * spv));            // feature exponent scale
    float twoco = (float)(2.0 * LOG2E / (sqv * sqv));   // org dot exponent scale
    float epsv = (float)eps, ome = (float)(1.0 - eps);

    // ---- epilogue: kernel values in-register, E2 LDS tile for row sums ----
    float* E2 = (float*)smem;

    double bsum = 0.0, trsum = 0.0;
    float colacc = 0.0f;
    int cl = wc4 * 32 + (lane & 31);
    float wb = wOrg[j0 + cl];
    float nbF = normF[j0 + cl];

    auto evalacc = [&](const v16f& aG, const v16f& aF, int rbase) {
        float4 wa4[4], na4[4];
#pragma unroll
        for (int q = 0; q < 4; ++q) {
            int rb = i0 + rbase + 4 * (lane >> 5) + 8 * q;
            wa4[q] = *(const float4*)&wOrg[rb];
            na4[q] = *(const float4*)&normF[rb];
        }
#pragma unroll
        for (int reg = 0; reg < 16; ++reg) {
            int rl = rbase + 4 * (lane >> 5) + (reg & 3) + 8 * (reg >> 2);
            float wa = ((const float*)&wa4[reg >> 2])[reg & 3];
            float naA = ((const float*)&na4[reg >> 2])[reg & 3];
            float dfeat = fmaxf(naA + nbF - 2.0f * aF[reg], 0.0f);
            float e2v = exp2f(-dfeat * cf);
            float kv = wa * wb * exp2f(aG[reg] * twoco) * (ome * e2v + epsv);
            if (isDiag && rl == cl) kv = 0.0f;
            if (isTrace && cl == rl) trsum += (double)kv;
            bsum += (double)kv;
            colacc += kv;
            E2[rl * 128 + cl] = kv;
        }
    };
    evalacc(accG0, accF0, wr2 * 64);
    evalacc(accG1, accF1, wr2 * 64 + 32);
    __syncthreads();

    // row sums: 4 threads per row; rotation (q<<1|row&1) -> 8 distinct bank
    // quads per 8-lane group (conflict-free)
    {
        int row = tid >> 2, q = tid & 3;
        int rot = ((q << 1) | (row & 1));
        float s = 0.0f;
#pragma unroll
        for (int c = 0; c < 8; ++c) {
            int cc = (c + rot) & 7;
            float4 v = *(const float4*)&E2[row * 128 + q * 32 + cc * 4];
            s += v.x + v.y + v.z + v.w;
        }
        s += __shfl_xor(s, 1);
        s += __shfl_xor(s, 2);
        if (q == 0) atomicAdd(&D8[i0 + row], sgn * s);
    }

    // column sums (skip for diagonal tiles: rows already cover both triangles)
    if (!isDiag) {
        atomicAdd(&D8[j0 + cl], sgn * colacc);
    }

    // block reduce bsum (+ trace): wave shuffle then 8-way LDS
#pragma unroll
    for (int off = 32; off > 0; off >>= 1) bsum += __shfl_down(bsum, off);
    if (isTrace) {
#pragma unroll
        for (int off = 32; off > 0; off >>= 1) trsum += __shfl_down(trsum, off);
    }
    __syncthreads();               // E2 reads done; reuse smem as dred
    double* dred = (double*)smem;
    if (lane == 0) { dred[w] = bsum; dred[8 + w] = trsum; }
    __syncthreads();
    if (tid == 0) {
        double wgt = (sameHalf && !isDiag) ? 2.0 : 1.0;
        double t0 = 0.0, t1 = 0.0;
#pragma unroll
        for (int q = 0; q < 8; ++q) { t0 += dred[q]; t1 += dred[8 + q]; }
        atomicAdd(&S[region], wgt * t0);
        if (isTrace) atomicAdd(&S[3], t1);
    }
}

// ---------------- final scalar assembly ----------------
__global__ __launch_bounds__(256)
void final_kernel(const float* __restrict__ D8, const double* __restrict__ S,
                  float* __restrict__ out)
{
    __shared__ double buf[512];
    int tid = threadIdx.x;
    double sD = 0, sD2 = 0;
    for (int i = tid; i < 4096; i += 256) {
        double d = (double)D8[i] + (double)D8[i + 4096];
        sD += d; sD2 += d * d;
    }
    buf[tid] = sD; buf[256 + tid] = sD2;
    __syncthreads();
    for (int s = 128; s > 0; s >>= 1) {
        if (tid < s) { buf[tid] += buf[tid + s]; buf[256 + tid] += buf[256 + tid + s]; }
        __syncthreads();
    }
    if (tid == 0) {
        double n = (double)N_S, D = n * (n - 1.0);
        double xx = S[0] / D, yy = S[1] / D, xy = (S[2] - S[3]) / D;
        double mmd2 = xx - 2.0 * xy + yy;
        double sumd = buf[0], sumd2 = buf[256];
        double sumh = 2.0 * n + sumd;                    // hs_i = 2 + delta_i
        double sumhs2 = 4.0 * n + 4.0 * sumd + sumd2;
        double n3 = n * n * n, n4 = n3 * n;
        double var = 4.0 / n3 * sumhs2 - 4.0 / n4 * sumh * sumh + 1e-8;
        out[0] = (float)mmd2;
        out[1] = (float)var;
    }
}

extern "C" void kernel_launch(void* const* d_in, const int* in_sizes, int n_in,
                              void* d_out, int out_size, void* d_ws, size_t ws_size,
                              hipStream_t stream)
{
    const float* X   = (const float*)d_in[0];
    const float* Y   = (const float*)d_in[1];
    const float* W1  = (const float*)d_in[2];
    const float* b1  = (const float*)d_in[3];
    const float* W2  = (const float*)d_in[4];
    const float* b2  = (const float*)d_in[5];
    const float* W3  = (const float*)d_in[6];
    const float* b3  = (const float*)d_in[7];
    const float* W4  = (const float*)d_in[8];
    const float* b4  = (const float*)d_in[9];
    const float* ep  = (const float*)d_in[10];
    const float* sq  = (const float*)d_in[11];
    const float* sph = (const float*)d_in[12];
    float* out = (float*)d_out;

    char* ws = (char*)d_ws;
    uint4*  PKT   = (uint4*)ws;                       // 48*8192*16 = 6291456
    float*  wOrg  = (float*)(ws + 6291456);           // 32768
    float*  normF = (float*)(ws + 6324224);           // 32768
    float*  D8    = (float*)(ws + 6356992);           // 32768
    double* S     = (double*)(ws + 6389760);          // 32 (Sxx, Syy, Sxy, trace)

    mlp_kernel<<<256, 256, 0, stream>>>(X, Y, W1, b1, W2, b2, W3, b3, W4, b4,
                                        sq, PKT, normF, wOrg, D8, S);

    pair_kernel<<<2080, 512, 0, stream>>>(PKT, normF, wOrg, ep, sq, sph, D8, S);

    final_kernel<<<1, 256, 0, stream>>>(D8, S, out);
}

// Round 10
// 174.830 us; speedup vs baseline: 1.1146x; 1.0103x over previous
//
#include <hip/hip_runtime.h>
#include <math.h>

// DeepMMD, round 12: joint symmetric 8192x8192 pass, 128x128 tiles (2080 blocks).
//  - pair_kernel retiled: 256 threads / 4 waves, each wave owns a 64x64 output
//    quadrant (2x2 wave grid). Per org K=16 step: 2A+2B frag reads -> 4 MFMA
//    (1.0 read/MFMA, was 1.5). Block frag reads 576 -> 384 b128; MFMA, staging,
//    epilogue totals unchanged.
//  - PKT[48][8192] uint4 transposed fragment store (coalesced staging, r11) +
//    slot-major LDS (conflict-free ds_reads, r10) retained.
//  - org dot pure-f16 + exact fp64 norms; feat dot hi/lo 3-product (r6/r9).
//  - one barrier per K-iter, vmcnt(0)-own-loads pipeline (r8), XCD swizzle.

#define N_S 4096
#define LOG2E 1.4426950408889634

typedef _Float16 v8h __attribute__((ext_vector_type(8)));
typedef float v16f __attribute__((ext_vector_type(16)));

union U16 { uint4 u; v8h h; };

__device__ __forceinline__ void pack_hilo(const float* fv, uint4* hi, uint4* lo) {
    U16 H, L;
#pragma unroll
    for (int u = 0; u < 8; ++u) {
        _Float16 h = (_Float16)fv[u];
        H.h[u] = h;
        L.h[u] = (_Float16)(fv[u] - (float)h);
    }
    *hi = H.u; *lo = L.u;
}

__device__ __forceinline__ uint4 pack_hi(const float* fv) {
    U16 H;
#pragma unroll
    for (int u = 0; u < 8; ++u) H.h[u] = (_Float16)fv[u];
    return H.u;
}

__device__ __forceinline__ void gload16(const void* g, void* lds) {
    __builtin_amdgcn_global_load_lds(
        (const __attribute__((address_space(1))) unsigned int*)g,
        (__attribute__((address_space(3))) unsigned int*)lds, 16, 0, 0);
}

// ---------------- MLP (fp64 internals), 8-way k-split ----------------
// -> PKT[48][8192] uint4 (column-major fragments): org cols 0..31 (slot g*4+u,
//    hi only), feat cols 32..47 (32+(g>>2)*8+(g&3) hi, +4 lo).
// also normF[8192], wOrg[8192]; zeroes D8[8192] and S[4].
__global__ __launch_bounds__(256)
void mlp_kernel(const float* __restrict__ X, const float* __restrict__ Y,
                const float* __restrict__ W1, const float* __restrict__ b1,
                const float* __restrict__ W2, const float* __restrict__ b2,
                const float* __restrict__ W3, const float* __restrict__ b3,
                const float* __restrict__ W4, const float* __restrict__ b4,
                const float* __restrict__ sq,
                uint4* __restrict__ PKT, float* __restrict__ normF,
                float* __restrict__ wOrg,
                float* __restrict__ D8, double* __restrict__ S)
{
    __shared__ double sW1[8 * 330];
    __shared__ double sW2[100], sW3[100], sW4[500];
    __shared__ double sb1[10], sb2[10], sb3[10], sb4[50];
    int tid = threadIdx.x;
    int gt = blockIdx.x * 256 + tid;

    // workspace zeroing (replaces hipMemsetAsync)
    if (gt < 8192) D8[gt] = 0.0f;
    else if (gt < 8196) S[gt - 8192] = 0.0;

    {
        int kg = tid >> 5, kl = tid & 31;
#pragma unroll
        for (int j = 0; j < 10; ++j)
            sW1[kg * 330 + kl * 10 + j] = (double)W1[tid * 10 + j];
    }
    for (int i = tid; i < 100; i += 256) { sW2[i] = (double)W2[i]; sW3[i] = (double)W3[i]; }
    for (int i = tid; i < 500; i += 256) sW4[i] = (double)W4[i];
    if (tid < 10) { sb1[tid] = (double)b1[tid]; sb2[tid] = (double)b2[tid]; sb3[tid] = (double)b3[tid]; }
    if (tid < 50) sb4[tid] = (double)b4[tid];
    __syncthreads();

    int r = gt >> 3, g = gt & 7;
    const float* xr = (r < N_S) ? (X + (size_t)r * 256) : (Y + (size_t)(r - N_S) * 256);
    const float* xrg = xr + g * 32;
    const double* w1g = sW1 + g * 330;

    float xl[32];
    double z[10];
#pragma unroll
    for (int j = 0; j < 10; ++j) z[j] = 0.0;
    double nrm = 0.0;
    for (int k4 = 0; k4 < 32; k4 += 4) {
        float4 xv4 = *(const float4*)(xrg + k4);
        xl[k4] = xv4.x; xl[k4 + 1] = xv4.y; xl[k4 + 2] = xv4.z; xl[k4 + 3] = xv4.w;
        double xv[4] = {(double)xv4.x, (double)xv4.y, (double)xv4.z, (double)xv4.w};
#pragma unroll
        for (int u = 0; u < 4; ++u) {
            nrm += xv[u] * xv[u];
#pragma unroll
            for (int j = 0; j < 10; ++j) z[j] += xv[u] * w1g[(k4 + u) * 10 + j];
        }
    }
    // pack org fragments: columns g*4+u, row r
    {
#pragma unroll
        for (int u = 0; u < 4; ++u)
            PKT[(size_t)(g * 4 + u) * 8192 + r] = pack_hi(&xl[u * 8]);
    }

#pragma unroll
    for (int off = 1; off < 8; off <<= 1) {
        nrm += __shfl_xor(nrm, off);
#pragma unroll
        for (int j = 0; j < 10; ++j) z[j] += __shfl_xor(z[j], off);
    }
#pragma unroll
    for (int j = 0; j < 10; ++j) z[j] += sb1[j];
#pragma unroll
    for (int j = 0; j < 10; ++j) z[j] = fmax(z[j], 0.0) + log1p(exp(-fabs(z[j])));

    double z2[10];
#pragma unroll
    for (int j = 0; j < 10; ++j) z2[j] = sb2[j];
#pragma unroll
    for (int k = 0; k < 10; ++k)
#pragma unroll
        for (int j = 0; j < 10; ++j) z2[j] += z[k] * sW2[k * 10 + j];
#pragma unroll
    for (int j = 0; j < 10; ++j) z2[j] = fmax(z2[j], 0.0) + log1p(exp(-fabs(z2[j])));

    double z3[10];
#pragma unroll
    for (int j = 0; j < 10; ++j) z3[j] = sb3[j];
#pragma unroll
    for (int k = 0; k < 10; ++k)
#pragma unroll
        for (int j = 0; j < 10; ++j) z3[j] += z2[k] * sW3[k * 10 + j];
#pragma unroll
    for (int j = 0; j < 10; ++j) z3[j] = fmax(z3[j], 0.0) + log1p(exp(-fabs(z3[j])));

    // all 8 lanes compute all 50 f values (identical fp64); lane g keeps j in [8g,8g+8)
    double nf = 0.0;
    float ff[8];
#pragma unroll
    for (int u = 0; u < 8; ++u) ff[u] = 0.0f;
#pragma unroll
    for (int j = 0; j < 50; ++j) {
        double f = sb4[j];
#pragma unroll
        for (int k = 0; k < 10; ++k) f += z3[k] * sW4[k * 50 + j];
        nf += f * f;
        if ((j >> 3) == g) ff[j & 7] = (float)f;
    }
    {
        uint4 hi, lo;
        pack_hilo(ff, &hi, &lo);
        int colh = 32 + (g >> 2) * 8 + (g & 3);
        PKT[(size_t)colh * 8192 + r] = hi;
        PKT[(size_t)(colh + 4) * 8192 + r] = lo;
    }

    if (g == 0) {
        double sqv = (double)sq[0];
        double co = LOG2E / (sqv * sqv);
        wOrg[r] = (float)exp2(-nrm * co);
    }
    if (g == 1) normF[r] = (float)nf;
}

// ---------------- helpers ----------------
// slot-major LDS read: buf[g*128 + s] (conflict-free: bank quad = s mod 8)
__device__ __forceinline__ v8h ldsm(const uint4* buf, int s, int g) {
    U16 t; t.u = buf[g * 128 + s];
    return t.h;
}

// ---------------- joint pairwise pass (256 threads / 4 waves) ----------------
__global__ __launch_bounds__(256, 2)
void pair_kernel(const uint4* __restrict__ PKT, const float* __restrict__ normF,
                 const float* __restrict__ wOrg,
                 const float* __restrict__ ep, const float* __restrict__ sq,
                 const float* __restrict__ sph,
                 float* __restrict__ D8, double* __restrict__ S)
{
    // LDS: dbuf half hb at smem+hb*32768:
    //   A[8 slots][128 rows]u4 (16K) @0 + B (16K) @16384
    // epilogue: E2[128][128] f32 = 65536; dred 8 f64 (overlaid after sync)
    __shared__ __align__(16) char smem[65536];

    int tid = threadIdx.x;
    int lane = tid & 63, w = tid >> 6;
    int wr = w >> 1, wc = w & 1;            // 2x2 wave grid, 64x64 per wave

    // XCD-chunked swizzle (2080 = 8 * 260, bijective) + closed-form triangle decode
    int orig = blockIdx.x;
    int L = (orig & 7) * 260 + (orig >> 3);
    int it = (int)((129.0 - sqrt(16641.0 - 8.0 * (double)L)) * 0.5);
    while (it * (129 - it) / 2 > L) --it;
    while ((it + 1) * (128 - it) / 2 <= L) ++it;
    int jt = it + (L - it * (129 - it) / 2);
    int i0 = it * 128, j0 = jt * 128;

    // stage iteration t into buffer half hb: linear LDS dest addr16 = u,
    // thread pass u = i*256+tid -> slot u>>7 = i*2+(w>>1), row u&127 =
    // (w&1)*64+lane; global src PKT[col][i0/j0 + row] -> consecutive lanes read
    // consecutive 16B (fully coalesced 2KB segments).
    auto stage = [&](int t, int hb) {
        char* Ab = smem + hb * 32768;
        char* Bb = Ab + 16384;
        int soff = (t < 4) ? t * 8 : 32 + (t - 4) * 8;
#pragma unroll
        for (int i = 0; i < 4; ++i) {
            int u = i * 256 + tid;
            int row = u & 127, s8 = u >> 7;
            const uint4* ga = &PKT[(size_t)(soff + s8) * 8192 + i0 + row];
            const uint4* gb = &PKT[(size_t)(soff + s8) * 8192 + j0 + row];
            char* la = Ab + (i * 256 + (w << 6)) * 16;   // wave-uniform base
            char* lb = Bb + (i * 256 + (w << 6)) * 16;
            gload16(ga, la);
            gload16(gb, lb);
        }
    };

    stage(0, 0);        // first loads fly while scalar setup below executes

    bool sameHalf = (jt < 32) || (it >= 32);
    bool isDiag = (it == jt);
    bool isTrace = (jt == it + 32);
    int region = (jt < 32) ? 0 : ((it >= 32) ? 1 : 2);
    float sgn = sameHalf ? 1.0f : -1.0f;

    int rs0 = wr * 64 + (lane & 31), rs1 = rs0 + 32;
    int cs0 = wc * 64 + (lane & 31), cs1 = cs0 + 32;

    // org: pure f16 single product, K=64 -> 4 ks x (2A+2B reads, 4 MFMA)
    auto mfma_org = [&](int hb, v16f& a00, v16f& a01, v16f& a10, v16f& a11) {
        const uint4* Ab = (const uint4*)(smem + hb * 32768);
        const uint4* Bb = (const uint4*)(smem + hb * 32768 + 16384);
#pragma unroll
        for (int ks = 0; ks < 4; ++ks) {
            int gl = ks * 2 + (lane >> 5);
            v8h ah0 = ldsm(Ab, rs0, gl), ah1 = ldsm(Ab, rs1, gl);
            v8h bh0 = ldsm(Bb, cs0, gl), bh1 = ldsm(Bb, cs1, gl);
            a00 = __builtin_amdgcn_mfma_f32_32x32x16_f16(ah0, bh0, a00, 0, 0, 0);
            a01 = __builtin_amdgcn_mfma_f32_32x32x16_f16(ah0, bh1, a01, 0, 0, 0);
            a10 = __builtin_amdgcn_mfma_f32_32x32x16_f16(ah1, bh0, a10, 0, 0, 0);
            a11 = __builtin_amdgcn_mfma_f32_32x32x16_f16(ah1, bh1, a11, 0, 0, 0);
        }
    };
    // feat: hi/lo 3-product (hi slots 0-3, lo slots 4-7), 8 reads -> 12 MFMA/ks
    auto mfma_feat = [&](int hb, v16f& a00, v16f& a01, v16f& a10, v16f& a11) {
        const uint4* Ab = (const uint4*)(smem + hb * 32768);
        const uint4* Bb = (const uint4*)(smem + hb * 32768 + 16384);
#pragma unroll
        for (int ks = 0; ks < 2; ++ks) {
            int gl = ks * 2 + (lane >> 5);
            v8h ah0 = ldsm(Ab, rs0, gl), ah1 = ldsm(Ab, rs1, gl);
            v8h al0 = ldsm(Ab, rs0, 4 + gl), al1 = ldsm(Ab, rs1, 4 + gl);
            v8h bh0 = ldsm(Bb, cs0, gl), bh1 = ldsm(Bb, cs1, gl);
            v8h bl0 = ldsm(Bb, cs0, 4 + gl), bl1 = ldsm(Bb, cs1, 4 + gl);
            a00 = __builtin_amdgcn_mfma_f32_32x32x16_f16(al0, bh0, a00, 0, 0, 0);
            a00 = __builtin_amdgcn_mfma_f32_32x32x16_f16(ah0, bl0, a00, 0, 0, 0);
            a00 = __builtin_amdgcn_mfma_f32_32x32x16_f16(ah0, bh0, a00, 0, 0, 0);
            a01 = __builtin_amdgcn_mfma_f32_32x32x16_f16(al0, bh1, a01, 0, 0, 0);
            a01 = __builtin_amdgcn_mfma_f32_32x32x16_f16(ah0, bl1, a01, 0, 0, 0);
            a01 = __builtin_amdgcn_mfma_f32_32x32x16_f16(ah0, bh1, a01, 0, 0, 0);
            a10 = __builtin_amdgcn_mfma_f32_32x32x16_f16(al1, bh0, a10, 0, 0, 0);
            a10 = __builtin_amdgcn_mfma_f32_32x32x16_f16(ah1, bl0, a10, 0, 0, 0);
            a10 = __builtin_amdgcn_mfma_f32_32x32x16_f16(ah1, bh0, a10, 0, 0, 0);
            a11 = __builtin_amdgcn_mfma_f32_32x32x16_f16(al1, bh1, a11, 0, 0, 0);
            a11 = __builtin_amdgcn_mfma_f32_32x32x16_f16(ah1, bl1, a11, 0, 0, 0);
            a11 = __builtin_amdgcn_mfma_f32_32x32x16_f16(ah1, bh1, a11, 0, 0, 0);
        }
    };

    v16f aG00{}, aG01{}, aG10{}, aG11{};
    v16f aF00{}, aF01{}, aF10{}, aF11{};

    // ---- K-loop: 4 org (K=64) + 2 feat iterations, ONE barrier/iter ----
    // body t: [vmcnt(0) own t-loads; barrier (=> all waves' t-loads landed AND
    // all waves done MFMA(t-1) on hb^1); stage(t+1) into hb^1; MFMA(t) on hb]
#pragma unroll
    for (int t = 0; t < 6; ++t) {
        int hb = t & 1;
        asm volatile("s_waitcnt vmcnt(0)" ::: "memory");
        __builtin_amdgcn_sched_barrier(0);
        __builtin_amdgcn_s_barrier();
        __builtin_amdgcn_sched_barrier(0);
        if (t < 5) stage(t + 1, hb ^ 1);
        __builtin_amdgcn_s_setprio(1);
        if (t < 4) mfma_org(hb, aG00, aG01, aG10, aG11);
        else       mfma_feat(hb, aF00, aF01, aF10, aF11);
        __builtin_amdgcn_s_setprio(0);
    }
    __syncthreads();    // all waves' ds_reads done before E2 overwrites buffers

    // scalar params
    double epd = (double)ep[0];
    double eps = 1.0 / (1.0 + exp(-epd));
    double sqv = (double)sq[0], spv = (double)sph[0];
    float cf = (float)(LOG2E / (spv * spv));            // feature exponent scale
    float twoco = (float)(2.0 * LOG2E / (sqv * sqv));   // org dot exponent scale
    float epsv = (float)eps, ome = (float)(1.0 - eps);

    // ---- epilogue: kernel values in-register, E2 LDS tile for row sums ----
    float* E2 = (float*)smem;

    double bsum = 0.0, trsum = 0.0;
    float colacc0 = 0.0f, colacc1 = 0.0f;
    int cl0 = wc * 64 + (lane & 31), cl1 = cl0 + 32;
    float wb0 = wOrg[j0 + cl0], nb0 = normF[j0 + cl0];
    float wb1 = wOrg[j0 + cl1], nb1 = normF[j0 + cl1];

    auto evalrow = [&](const v16f& g0, const v16f& f0,
                       const v16f& g1, const v16f& f1, int rbase) {
        float4 wa4[4], na4[4];
#pragma unroll
        for (int q = 0; q < 4; ++q) {
            int rb = i0 + rbase + 4 * (lane >> 5) + 8 * q;
            wa4[q] = *(const float4*)&wOrg[rb];
            na4[q] = *(const float4*)&normF[rb];
        }
#pragma unroll
        for (int reg = 0; reg < 16; ++reg) {
            int rl = rbase + 4 * (lane >> 5) + (reg & 3) + 8 * (reg >> 2);
            float wa = ((const float*)&wa4[reg >> 2])[reg & 3];
            float naA = ((const float*)&na4[reg >> 2])[reg & 3];
            {
                float dfeat = fmaxf(naA + nb0 - 2.0f * f0[reg], 0.0f);
                float e2v = exp2f(-dfeat * cf);
                float kv = wa * wb0 * exp2f(g0[reg] * twoco) * (ome * e2v + epsv);
                if (isDiag && rl == cl0) kv = 0.0f;
                if (isTrace && cl0 == rl) trsum += (double)kv;
                bsum += (double)kv;
                colacc0 += kv;
                E2[rl * 128 + cl0] = kv;
            }
            {
                float dfeat = fmaxf(naA + nb1 - 2.0f * f1[reg], 0.0f);
                float e2v = exp2f(-dfeat * cf);
                float kv = wa * wb1 * exp2f(g1[reg] * twoco) * (ome * e2v + epsv);
                if (isDiag && rl == cl1) kv = 0.0f;
                if (isTrace && cl1 == rl) trsum += (double)kv;
                bsum += (double)kv;
                colacc1 += kv;
                E2[rl * 128 + cl1] = kv;
            }
        }
    };
    evalrow(aG00, aF00, aG01, aF01, wr * 64);
    evalrow(aG10, aF10, aG11, aF11, wr * 64 + 32);
    __syncthreads();

    // row sums: 2 threads per row; per-row rotation spreads bank quads
    {
        int row = tid >> 1, half = tid & 1;
        float s = 0.0f;
#pragma unroll
        for (int c = 0; c < 16; ++c) {
            int cc = (c + row) & 15;
            float4 v = *(const float4*)&E2[row * 128 + half * 64 + cc * 4];
            s += v.x + v.y + v.z + v.w;
        }
        s += __shfl_xor(s, 1);
        if (half == 0) atomicAdd(&D8[i0 + row], sgn * s);
    }

    // column sums (skip for diagonal tiles: rows already cover both triangles)
    if (!isDiag) {
        atomicAdd(&D8[j0 + cl0], sgn * colacc0);
        atomicAdd(&D8[j0 + cl1], sgn * colacc1);
    }

    // block reduce bsum (+ trace): wave shuffle then 4-way LDS
#pragma unroll
    for (int off = 32; off > 0; off >>= 1) bsum += __shfl_down(bsum, off);
    if (isTrace) {
#pragma unroll
        for (int off = 32; off > 0; off >>= 1) trsum += __shfl_down(trsum, off);
    }
    __syncthreads();               // E2 reads done; reuse smem as dred
    double* dred = (double*)smem;
    if (lane == 0) { dred[w] = bsum; dred[4 + w] = trsum; }
    __syncthreads();
    if (tid == 0) {
        double wgt = (sameHalf && !isDiag) ? 2.0 : 1.0;
        atomicAdd(&S[region], wgt * (dred[0] + dred[1] + dred[2] + dred[3]));
        if (isTrace) atomicAdd(&S[3], dred[4] + dred[5] + dred[6] + dred[7]);
    }
}

// ---------------- final scalar assembly ----------------
__global__ __launch_bounds__(256)
void final_kernel(const float* __restrict__ D8, const double* __restrict__ S,
                  float* __restrict__ out)
{
    __shared__ double buf[512];
    int tid = threadIdx.x;
    double sD = 0, sD2 = 0;
    for (int i = tid; i < 4096; i += 256) {
        double d = (double)D8[i] + (double)D8[i + 4096];
        sD += d; sD2 += d * d;
    }
    buf[tid] = sD; buf[256 + tid] = sD2;
    __syncthreads();
    for (int s = 128; s > 0; s >>= 1) {
        if (tid < s) { buf[tid] += buf[tid + s]; buf[256 + tid] += buf[256 + tid + s]; }
        __syncthreads();
    }
    if (tid == 0) {
        double n = (double)N_S, D = n * (n - 1.0);
        double xx = S[0] / D, yy = S[1] / D, xy = (S[2] - S[3]) / D;
        double mmd2 = xx - 2.0 * xy + yy;
        double sumd = buf[0], sumd2 = buf[256];
        double sumh = 2.0 * n + sumd;                    // hs_i = 2 + delta_i
        double sumhs2 = 4.0 * n + 4.0 * sumd + sumd2;
        double n3 = n * n * n, n4 = n3 * n;
        double var = 4.0 / n3 * sumhs2 - 4.0 / n4 * sumh * sumh + 1e-8;
        out[0] = (float)mmd2;
        out[1] = (float)var;
    }
}

extern "C" void kernel_launch(void* const* d_in, const int* in_sizes, int n_in,
                              void* d_out, int out_size, void* d_ws, size_t ws_size,
                              hipStream_t stream)
{
    const float* X   = (const float*)d_in[0];
    const float* Y   = (const float*)d_in[1];
    const float* W1  = (const float*)d_in[2];
    const float* b1  = (const float*)d_in[3];
    const float* W2  = (const float*)d_in[4];
    const float* b2  = (const float*)d_in[5];
    const float* W3  = (const float*)d_in[6];
    const float* b3  = (const float*)d_in[7];
    const float* W4  = (const float*)d_in[8];
    const float* b4  = (const float*)d_in[9];
    const float* ep  = (const float*)d_in[10];
    const float* sq  = (const float*)d_in[11];
    const float* sph = (const float*)d_in[12];
    float* out = (float*)d_out;

    char* ws = (char*)d_ws;
    uint4*  PKT   = (uint4*)ws;                       // 48*8192*16 = 6291456
    float*  wOrg  = (float*)(ws + 6291456);           // 32768
    float*  normF = (float*)(ws + 6324224);           // 32768
    float*  D8    = (float*)(ws + 6356992);           // 32768
    double* S     = (double*)(ws + 6389760);          // 32 (Sxx, Syy, Sxy, trace)

    mlp_kernel<<<256, 256, 0, stream>>>(X, Y, W1, b1, W2, b2, W3, b3, W4, b4,
                                        sq, PKT, normF, wOrg, D8, S);

    pair_kernel<<<2080, 256, 0, stream>>>(PKT, normF, wOrg, ep, sq, sph, D8, S);

    final_kernel<<<1, 256, 0, stream>>>(D8, S, out);
}